// Round 2
// baseline (3175.049 us; speedup 1.0000x reference)
//
#include <hip/hip_runtime.h>

// WasserIndexGen: Wasserstein barycenter Sinkhorn (N=4096, NBB=64, <=30 iters).
// Inputs: a(4096), M(4096x4096), b(4096x64), lbd(64), reg(1)  -- all f32.
// Output: scalar sum((yhat - a)^2).
//
// Design: C = exp(-M/reg) is NEVER materialized -- both GEMMs fuse the exp
// into LDS staging (reads M row-major coalesced in both orientations; the
// C^T GEMM transposes tiles in LDS with an XOR swizzle).  Split-K writes
// deterministic partial slices (no atomics); the consumer kernels reduce.
// Device-side while_loop control via flags in S, double-buffered per parity,
// so the captured fixed 30-iteration launch sequence is data-independent.
//
// ws layout (floats): part[16*N*64] (split-K partials, reused by both GEMMs),
// r[N*64], u[N*64], v[N*64], yhat[N], yhat_new[N], S[64].  ~19.3 MB.

constexpr int NV     = 4096;
constexpr int NBB_   = 64;
constexpr int ITERS  = 30;
constexpr int KSPLIT = 16;              // 16 k-slices of 256
constexpr int PART   = NV * NBB_;       // floats per partial slice

__device__ __forceinline__ bool finitef(float x) {
  return __builtin_fabsf(x) <= 3.402823466e38f;  // false for NaN/inf
}

// ---------------- init: iterates + control scalars --------------------------
__global__ void k_init(float* __restrict__ u, float* __restrict__ v,
                       float* __restrict__ yhat, float* __restrict__ S) {
  int idx = blockIdx.x * blockDim.x + threadIdx.x;
  if (idx < NV * NBB_) { u[idx] = 1.0f; v[idx] = 1.0f; }
  if (idx < NV) yhat[idx] = 0.0f;
  if (idx == 0) {
    int* Si = (int*)S;
    S[0]  = 1.0f;          // err
    Si[1] = 0;             // cpt
    Si[2] = 0;             // broke
    Si[3] = 1;             // active slot 0
    Si[4] = 0;             // active slot 1
    Si[5] = 0; Si[6] = 0;  // badCu flag per slot
    Si[7] = 0; Si[8] = 0;  // nonfinite flag per slot
#pragma unroll
    for (int q = 9; q < 17; ++q) S[q] = 0.0f;  // err sums per slot (4 each)
  }
}

// ---------------- GEMM 1: OutP[ks] = exp(-M/reg)[rows] @ B  -----------------
// grid = 64 row-tiles x 16 k-splits = 1024 blocks (4/CU), 256 threads.
// Thread: 4 rows (rg+16i) x 4 cols (4c+j).  Deterministic partial epilogue.
__global__ __launch_bounds__(256, 4) void k_gemm_e(const float* __restrict__ M,
                                                   const float* __restrict__ regp,
                                                   const float* __restrict__ B,
                                                   float* __restrict__ OutP,
                                                   const int* __restrict__ act) {
  if (*act == 0) return;
  __shared__ float bs[64 * NBB_];
  __shared__ float as[64][72];          // pad 72: conflict-free b128 reads
  const float ninv = -1.0f / regp[0];   // exp(-m/reg) = exp(m * ninv)
  const int rt = blockIdx.x & 63;
  const int ks = blockIdx.x >> 6;
  const int r0 = rt * 64;
  const int k0 = ks * 256;
  const int t  = threadIdx.x;
  const int c  = t & 15;
  const int rg = t >> 4;
  float acc[4][4] = {};
  for (int ck = 0; ck < 4; ++ck) {
    const int kb = k0 + ck * 64;
    const float4* Bv = (const float4*)(B + kb * NBB_);
    float4* Sv = (float4*)bs;
#pragma unroll
    for (int s = 0; s < 4; ++s) Sv[s * 256 + t] = Bv[s * 256 + t];
#pragma unroll
    for (int s = 0; s < 4; ++s) {
      int l = s * 256 + t;
      int row = l >> 4, c4 = l & 15;
      float4 m4 = *(const float4*)&M[(size_t)(r0 + row) * NV + kb + c4 * 4];
      float4 e4;
      e4.x = __expf(m4.x * ninv);
      e4.y = __expf(m4.y * ninv);
      e4.z = __expf(m4.z * ninv);
      e4.w = __expf(m4.w * ninv);
      *(float4*)&as[row][c4 * 4] = e4;
    }
    __syncthreads();
#pragma unroll 2
    for (int kk = 0; kk < 64; kk += 4) {
      float4 b0 = *(float4*)&bs[(kk + 0) * NBB_ + c * 4];
      float4 b1 = *(float4*)&bs[(kk + 1) * NBB_ + c * 4];
      float4 b2 = *(float4*)&bs[(kk + 2) * NBB_ + c * 4];
      float4 b3 = *(float4*)&bs[(kk + 3) * NBB_ + c * 4];
#pragma unroll
      for (int i = 0; i < 4; ++i) {
        float4 a4 = *(float4*)&as[rg + 16 * i][kk];
        acc[i][0] = fmaf(a4.x, b0.x, acc[i][0]);
        acc[i][1] = fmaf(a4.x, b0.y, acc[i][1]);
        acc[i][2] = fmaf(a4.x, b0.z, acc[i][2]);
        acc[i][3] = fmaf(a4.x, b0.w, acc[i][3]);
        acc[i][0] = fmaf(a4.y, b1.x, acc[i][0]);
        acc[i][1] = fmaf(a4.y, b1.y, acc[i][1]);
        acc[i][2] = fmaf(a4.y, b1.z, acc[i][2]);
        acc[i][3] = fmaf(a4.y, b1.w, acc[i][3]);
        acc[i][0] = fmaf(a4.z, b2.x, acc[i][0]);
        acc[i][1] = fmaf(a4.z, b2.y, acc[i][1]);
        acc[i][2] = fmaf(a4.z, b2.z, acc[i][2]);
        acc[i][3] = fmaf(a4.z, b2.w, acc[i][3]);
        acc[i][0] = fmaf(a4.w, b3.x, acc[i][0]);
        acc[i][1] = fmaf(a4.w, b3.y, acc[i][1]);
        acc[i][2] = fmaf(a4.w, b3.z, acc[i][2]);
        acc[i][3] = fmaf(a4.w, b3.w, acc[i][3]);
      }
    }
    __syncthreads();
  }
#pragma unroll
  for (int i = 0; i < 4; ++i) {
    const int row = r0 + rg + 16 * i;
    float4 o = make_float4(acc[i][0], acc[i][1], acc[i][2], acc[i][3]);
    *(float4*)&OutP[(size_t)ks * PART + row * NBB_ + c * 4] = o;
  }
}

// ---------------- GEMM 2: OutP[ks] = exp(-M/reg)^T[rows] @ B ----------------
// Same shape; A-tile transposed during staging with XOR-swizzled LDS layout:
// element (j_local, i_local) at as[j][ ((i>>2)^(j>>2))<<2 | (i&3) ].
// Writes: 2-way bank aliasing (free); reads: conflict-free b128.
__global__ __launch_bounds__(256, 4) void k_gemm_te(const float* __restrict__ M,
                                                    const float* __restrict__ regp,
                                                    const float* __restrict__ B,
                                                    float* __restrict__ OutP,
                                                    const int* __restrict__ act) {
  if (*act == 0) return;
  __shared__ float bs[64 * NBB_];
  __shared__ float as[64][72];
  const float ninv = -1.0f / regp[0];
  const int rt = blockIdx.x & 63;
  const int ks = blockIdx.x >> 6;
  const int r0 = rt * 64;               // output rows = columns of M
  const int k0 = ks * 256;              // k = rows of M
  const int t  = threadIdx.x;
  const int c  = t & 15;
  const int rg = t >> 4;
  float acc[4][4] = {};
  for (int ck = 0; ck < 4; ++ck) {
    const int kb = k0 + ck * 64;
    const float4* Bv = (const float4*)(B + kb * NBB_);
    float4* Sv = (float4*)bs;
#pragma unroll
    for (int s = 0; s < 4; ++s) Sv[s * 256 + t] = Bv[s * 256 + t];
#pragma unroll
    for (int s = 0; s < 4; ++s) {
      int l = s * 256 + t;
      int row = l >> 4, c4 = l & 15;    // row = i_local, cols j = 4c4+q
      float4 m4 = *(const float4*)&M[(size_t)(kb + row) * NV + r0 + c4 * 4];
      float4 e4;
      e4.x = __expf(m4.x * ninv);
      e4.y = __expf(m4.y * ninv);
      e4.z = __expf(m4.z * ninv);
      e4.w = __expf(m4.w * ninv);
      const int col = (((row >> 2) ^ c4) << 2) | (row & 3);
      as[4 * c4 + 0][col] = e4.x;
      as[4 * c4 + 1][col] = e4.y;
      as[4 * c4 + 2][col] = e4.z;
      as[4 * c4 + 3][col] = e4.w;
    }
    __syncthreads();
    const int rg2 = rg >> 2;
#pragma unroll 2
    for (int kk = 0; kk < 64; kk += 4) {
      float4 b0 = *(float4*)&bs[(kk + 0) * NBB_ + c * 4];
      float4 b1 = *(float4*)&bs[(kk + 1) * NBB_ + c * 4];
      float4 b2 = *(float4*)&bs[(kk + 2) * NBB_ + c * 4];
      float4 b3 = *(float4*)&bs[(kk + 3) * NBB_ + c * 4];
#pragma unroll
      for (int i = 0; i < 4; ++i) {
        const int sw = (rg2 + 4 * i) << 2;          // (j>>2)<<2 for this row
        float4 a4 = *(float4*)&as[rg + 16 * i][kk ^ sw];
        acc[i][0] = fmaf(a4.x, b0.x, acc[i][0]);
        acc[i][1] = fmaf(a4.x, b0.y, acc[i][1]);
        acc[i][2] = fmaf(a4.x, b0.z, acc[i][2]);
        acc[i][3] = fmaf(a4.x, b0.w, acc[i][3]);
        acc[i][0] = fmaf(a4.y, b1.x, acc[i][0]);
        acc[i][1] = fmaf(a4.y, b1.y, acc[i][1]);
        acc[i][2] = fmaf(a4.y, b1.z, acc[i][2]);
        acc[i][3] = fmaf(a4.y, b1.w, acc[i][3]);
        acc[i][0] = fmaf(a4.z, b2.x, acc[i][0]);
        acc[i][1] = fmaf(a4.z, b2.y, acc[i][1]);
        acc[i][2] = fmaf(a4.z, b2.z, acc[i][2]);
        acc[i][3] = fmaf(a4.z, b2.w, acc[i][3]);
        acc[i][0] = fmaf(a4.w, b3.x, acc[i][0]);
        acc[i][1] = fmaf(a4.w, b3.y, acc[i][1]);
        acc[i][2] = fmaf(a4.w, b3.z, acc[i][2]);
        acc[i][3] = fmaf(a4.w, b3.w, acc[i][3]);
      }
    }
    __syncthreads();
  }
#pragma unroll
  for (int i = 0; i < 4; ++i) {
    const int row = r0 + rg + 16 * i;
    float4 o = make_float4(acc[i][0], acc[i][1], acc[i][2], acc[i][3]);
    *(float4*)&OutP[(size_t)ks * PART + row * NBB_ + c * 4] = o;
  }
}

// ---------------- r = b / sum_ks(CuP), flag any(Cu == 0) --------------------
__global__ void k_div_red(const float4* __restrict__ b4, const float* __restrict__ CuP,
                          float4* __restrict__ r4, int* __restrict__ badflag,
                          const int* __restrict__ act) {
  if (*act == 0) return;
  const int idx = blockIdx.x * blockDim.x + threadIdx.x;  // < 65536 (float4)
  float4 s = make_float4(0.f, 0.f, 0.f, 0.f);
#pragma unroll
  for (int k = 0; k < KSPLIT; ++k) {
    const float4 p = *(const float4*)&CuP[(size_t)k * PART + idx * 4];
    s.x += p.x; s.y += p.y; s.z += p.z; s.w += p.w;
  }
  const float4 bb = b4[idx];
  float4 rr;
  rr.x = bb.x / s.x;
  rr.y = bb.y / s.y;
  rr.z = bb.z / s.z;
  rr.w = bb.w / s.w;
  r4[idx] = rr;
  if (s.x == 0.0f || s.y == 0.0f || s.z == 0.0f || s.w == 0.0f)
    atomicOr(badflag, 1);
}

// ---------------- per-row: reduce VaP -> v_new; yhat, u_new, err sums -------
// one wave per row (64 lanes = 64 topics); u,v updated IN PLACE (safe: once
// an iteration is bad, all later iterations are inactive and u,v never feed
// the output -- only yhat does, and yhat commit stays conditional).
__global__ void k_rowwise_red(const float* __restrict__ VaP, const float* __restrict__ lbd,
                              float* __restrict__ u, float* __restrict__ v,
                              float* __restrict__ yhnew, float* __restrict__ sums,
                              int* __restrict__ nonfin, const int* __restrict__ act) {
  if (*act == 0) return;
  const int lane = threadIdx.x & 63;
  const int row  = blockIdx.x * 4 + (threadIdx.x >> 6);
  const int idx  = row * NBB_ + lane;
  float vv = 0.0f;
#pragma unroll
  for (int k = 0; k < KSPLIT; ++k) vv += VaP[(size_t)k * PART + idx];
  float tsum = lbd[lane] * logf(vv);
#pragma unroll
  for (int o = 32; o > 0; o >>= 1) tsum += __shfl_xor(tsum, o);
  const float yhv = expf(tsum);          // prod_j v^lbd_j
  const float un  = yhv / vv;
  const float uo  = u[idx];
  const float vo  = v[idx];
  u[idx] = un;
  v[idx] = vv;
  if (lane == 0) yhnew[row] = yhv;
  if (!(finitef(un) && finitef(vv) && finitef(yhv))) atomicOr(nonfin, 1);
  const float du = un - uo;
  const float dv = vv - vo;
  float s0 = du * du, s1 = un * un, s2 = dv * dv, s3 = vv * vv;
#pragma unroll
  for (int o = 32; o > 0; o >>= 1) {
    s0 += __shfl_xor(s0, o);
    s1 += __shfl_xor(s1, o);
    s2 += __shfl_xor(s2, o);
    s3 += __shfl_xor(s3, o);
  }
  if (lane == 0) {
    atomicAdd(&sums[0], s0);
    atomicAdd(&sums[1], s1);
    atomicAdd(&sums[2], s2);
    atomicAdd(&sums[3], s3);
  }
}

// ---------------- commit: conditional yhat update + loop-control update -----
__global__ void k_commit(float* __restrict__ yhat, const float* __restrict__ yhnew,
                         float* __restrict__ S, int slot) {
  int* Si = (int*)S;
  const int active = Si[3 + slot];
  const int bad    = (Si[5 + slot] | Si[7 + slot]) != 0;
  const bool com   = (active != 0) && !bad;
  const int gid = blockIdx.x * blockDim.x + threadIdx.x;   // 4096 threads
  if (com && gid < NV) yhat[gid] = yhnew[gid];
  if (gid == 0) {
    if (active) {
      if (!bad) {
        const int cpt = Si[1];
        if (cpt % 10 == 0) {
          const float lhs = S[9 + 4 * slot + 0] / S[9 + 4 * slot + 1];
          const float rhs = S[9 + 4 * slot + 2] / S[9 + 4 * slot + 3];
          S[0] = lhs + rhs;              // err
        }
        Si[1] = cpt + 1;
      } else {
        Si[2] = 1;                       // broke
      }
    }
    const int ns = slot ^ 1;
    Si[3 + ns] = (S[0] > 1e-9f && Si[1] < ITERS && Si[2] == 0) ? 1 : 0;
    Si[5 + ns] = 0;
    Si[7 + ns] = 0;
    S[9 + 4 * ns + 0] = 0.0f;
    S[9 + 4 * ns + 1] = 0.0f;
    S[9 + 4 * ns + 2] = 0.0f;
    S[9 + 4 * ns + 3] = 0.0f;
  }
}

// ---------------- out = sum((yhat - a)^2) -----------------------------------
__global__ void k_final(const float* __restrict__ yhat, const float* __restrict__ a,
                        float* __restrict__ out) {
  __shared__ float red[4];
  const int t = threadIdx.x;
  float s = 0.0f;
  for (int i = t; i < NV; i += 256) {
    const float d = yhat[i] - a[i];
    s = fmaf(d, d, s);
  }
#pragma unroll
  for (int o = 32; o > 0; o >>= 1) s += __shfl_xor(s, o);
  if ((t & 63) == 0) red[t >> 6] = s;
  __syncthreads();
  if (t == 0) out[0] = red[0] + red[1] + red[2] + red[3];
}

extern "C" void kernel_launch(void* const* d_in, const int* in_sizes, int n_in,
                              void* d_out, int out_size, void* d_ws, size_t ws_size,
                              hipStream_t stream) {
  const float* a   = (const float*)d_in[0];
  const float* M   = (const float*)d_in[1];
  const float* b   = (const float*)d_in[2];
  const float* lbd = (const float*)d_in[3];
  const float* reg = (const float*)d_in[4];
  float* out = (float*)d_out;

  float* ws = (float*)d_ws;
  size_t o = 0;
  float* part = ws + o; o += (size_t)KSPLIT * PART;  // 16 MB, reused by both GEMMs
  float* r    = ws + o; o += PART;
  float* u    = ws + o; o += PART;
  float* v    = ws + o; o += PART;
  float* yh   = ws + o; o += NV;
  float* yhn  = ws + o; o += NV;
  float* S    = ws + o; o += 64;
  int* Si = (int*)S;

  k_init<<<dim3(1024), dim3(256), 0, stream>>>(u, v, yh, S);

  for (int it = 0; it < ITERS; ++it) {
    const int slot = it & 1;
    const int* act = (const int*)(Si + 3 + slot);
    k_gemm_e<<<dim3(1024), dim3(256), 0, stream>>>(M, reg, u, part, act);
    k_div_red<<<dim3(256), dim3(256), 0, stream>>>((const float4*)b, part,
                                                   (float4*)r, Si + 5 + slot, act);
    k_gemm_te<<<dim3(1024), dim3(256), 0, stream>>>(M, reg, r, part, act);
    k_rowwise_red<<<dim3(1024), dim3(256), 0, stream>>>(part, lbd, u, v, yhn,
                                                        S + 9 + 4 * slot,
                                                        Si + 7 + slot, act);
    k_commit<<<dim3(16), dim3(256), 0, stream>>>(yh, yhn, S, slot);
  }

  k_final<<<dim3(1), dim3(256), 0, stream>>>(yh, a, out);
}

// Round 3
// 1200.204 us; speedup vs baseline: 2.6454x; 2.6454x over previous
//
#include <hip/hip_runtime.h>

// WasserIndexGen: Wasserstein barycenter Sinkhorn (N=4096, NBB=64, <=30 iters).
// Inputs: a(4096), M(4096x4096), b(4096x64), lbd(64), reg(1)  -- all f32.
// Output: scalar sum((yhat - a)^2).
//
// Design: C = exp(-M/reg) is NEVER materialized -- both GEMMs fuse the exp
// into LDS staging (reads M row-major coalesced in both orientations; the
// C^T GEMM transposes tiles in LDS with an XOR swizzle).  Split-K writes
// deterministic partial slices (no atomics); the consumer kernels reduce.
// Err sums: per-block deterministic partials (NO same-address atomics --
// round-2 profile showed 213us/dispatch of pure atomic serialization),
// reduced by block 0 of k_commit.
// Device-side while_loop control via flags in S, double-buffered per parity,
// so the captured fixed 30-iteration launch sequence is data-independent.
//
// ws layout (floats): part[16*N*64] (split-K partials, reused by both GEMMs),
// r[N*64], u[N*64], v[N*64], yhat[N], yhat_new[N], S[64], Spart[1024*4].

constexpr int NV     = 4096;
constexpr int NBB_   = 64;
constexpr int ITERS  = 30;
constexpr int KSPLIT = 16;              // 16 k-slices of 256
constexpr int PART   = NV * NBB_;       // floats per partial slice

__device__ __forceinline__ bool finitef(float x) {
  return __builtin_fabsf(x) <= 3.402823466e38f;  // false for NaN/inf
}

// ---------------- init: iterates + control scalars --------------------------
__global__ void k_init(float* __restrict__ u, float* __restrict__ v,
                       float* __restrict__ yhat, float* __restrict__ S) {
  int idx = blockIdx.x * blockDim.x + threadIdx.x;
  if (idx < NV * NBB_) { u[idx] = 1.0f; v[idx] = 1.0f; }
  if (idx < NV) yhat[idx] = 0.0f;
  if (idx == 0) {
    int* Si = (int*)S;
    S[0]  = 1.0f;          // err
    Si[1] = 0;             // cpt
    Si[2] = 0;             // broke
    Si[3] = 1;             // active slot 0
    Si[4] = 0;             // active slot 1
    Si[5] = 0; Si[6] = 0;  // badCu flag per slot
    Si[7] = 0; Si[8] = 0;  // nonfinite flag per slot
  }
}

// ---------------- GEMM 1: OutP[ks] = exp(-M/reg)[rows] @ B  -----------------
// grid = 64 row-tiles x 16 k-splits = 1024 blocks (4/CU), 256 threads.
// Thread: 4 rows (rg+16i) x 4 cols (4c+j).  Deterministic partial epilogue.
__global__ __launch_bounds__(256, 4) void k_gemm_e(const float* __restrict__ M,
                                                   const float* __restrict__ regp,
                                                   const float* __restrict__ B,
                                                   float* __restrict__ OutP,
                                                   const int* __restrict__ act) {
  if (*act == 0) return;
  __shared__ float bs[64 * NBB_];
  __shared__ float as[64][72];          // pad 72: conflict-free b128 reads
  const float ninv = -1.0f / regp[0];   // exp(-m/reg) = exp(m * ninv)
  const int rt = blockIdx.x & 63;
  const int ks = blockIdx.x >> 6;
  const int r0 = rt * 64;
  const int k0 = ks * 256;
  const int t  = threadIdx.x;
  const int c  = t & 15;
  const int rg = t >> 4;
  float acc[4][4] = {};
  for (int ck = 0; ck < 4; ++ck) {
    const int kb = k0 + ck * 64;
    const float4* Bv = (const float4*)(B + kb * NBB_);
    float4* Sv = (float4*)bs;
#pragma unroll
    for (int s = 0; s < 4; ++s) Sv[s * 256 + t] = Bv[s * 256 + t];
#pragma unroll
    for (int s = 0; s < 4; ++s) {
      int l = s * 256 + t;
      int row = l >> 4, c4 = l & 15;
      float4 m4 = *(const float4*)&M[(size_t)(r0 + row) * NV + kb + c4 * 4];
      float4 e4;
      e4.x = __expf(m4.x * ninv);
      e4.y = __expf(m4.y * ninv);
      e4.z = __expf(m4.z * ninv);
      e4.w = __expf(m4.w * ninv);
      *(float4*)&as[row][c4 * 4] = e4;
    }
    __syncthreads();
#pragma unroll 2
    for (int kk = 0; kk < 64; kk += 4) {
      float4 b0 = *(float4*)&bs[(kk + 0) * NBB_ + c * 4];
      float4 b1 = *(float4*)&bs[(kk + 1) * NBB_ + c * 4];
      float4 b2 = *(float4*)&bs[(kk + 2) * NBB_ + c * 4];
      float4 b3 = *(float4*)&bs[(kk + 3) * NBB_ + c * 4];
#pragma unroll
      for (int i = 0; i < 4; ++i) {
        float4 a4 = *(float4*)&as[rg + 16 * i][kk];
        acc[i][0] = fmaf(a4.x, b0.x, acc[i][0]);
        acc[i][1] = fmaf(a4.x, b0.y, acc[i][1]);
        acc[i][2] = fmaf(a4.x, b0.z, acc[i][2]);
        acc[i][3] = fmaf(a4.x, b0.w, acc[i][3]);
        acc[i][0] = fmaf(a4.y, b1.x, acc[i][0]);
        acc[i][1] = fmaf(a4.y, b1.y, acc[i][1]);
        acc[i][2] = fmaf(a4.y, b1.z, acc[i][2]);
        acc[i][3] = fmaf(a4.y, b1.w, acc[i][3]);
        acc[i][0] = fmaf(a4.z, b2.x, acc[i][0]);
        acc[i][1] = fmaf(a4.z, b2.y, acc[i][1]);
        acc[i][2] = fmaf(a4.z, b2.z, acc[i][2]);
        acc[i][3] = fmaf(a4.z, b2.w, acc[i][3]);
        acc[i][0] = fmaf(a4.w, b3.x, acc[i][0]);
        acc[i][1] = fmaf(a4.w, b3.y, acc[i][1]);
        acc[i][2] = fmaf(a4.w, b3.z, acc[i][2]);
        acc[i][3] = fmaf(a4.w, b3.w, acc[i][3]);
      }
    }
    __syncthreads();
  }
#pragma unroll
  for (int i = 0; i < 4; ++i) {
    const int row = r0 + rg + 16 * i;
    float4 o = make_float4(acc[i][0], acc[i][1], acc[i][2], acc[i][3]);
    *(float4*)&OutP[(size_t)ks * PART + row * NBB_ + c * 4] = o;
  }
}

// ---------------- GEMM 2: OutP[ks] = exp(-M/reg)^T[rows] @ B ----------------
// Same shape; A-tile transposed during staging with XOR-swizzled LDS layout:
// element (j_local, i_local) at as[j][ ((i>>2)^(j>>2))<<2 | (i&3) ].
// Writes: 2-way bank aliasing (free); reads: conflict-free b128.
__global__ __launch_bounds__(256, 4) void k_gemm_te(const float* __restrict__ M,
                                                    const float* __restrict__ regp,
                                                    const float* __restrict__ B,
                                                    float* __restrict__ OutP,
                                                    const int* __restrict__ act) {
  if (*act == 0) return;
  __shared__ float bs[64 * NBB_];
  __shared__ float as[64][72];
  const float ninv = -1.0f / regp[0];
  const int rt = blockIdx.x & 63;
  const int ks = blockIdx.x >> 6;
  const int r0 = rt * 64;               // output rows = columns of M
  const int k0 = ks * 256;              // k = rows of M
  const int t  = threadIdx.x;
  const int c  = t & 15;
  const int rg = t >> 4;
  float acc[4][4] = {};
  for (int ck = 0; ck < 4; ++ck) {
    const int kb = k0 + ck * 64;
    const float4* Bv = (const float4*)(B + kb * NBB_);
    float4* Sv = (float4*)bs;
#pragma unroll
    for (int s = 0; s < 4; ++s) Sv[s * 256 + t] = Bv[s * 256 + t];
#pragma unroll
    for (int s = 0; s < 4; ++s) {
      int l = s * 256 + t;
      int row = l >> 4, c4 = l & 15;    // row = i_local, cols j = 4c4+q
      float4 m4 = *(const float4*)&M[(size_t)(kb + row) * NV + r0 + c4 * 4];
      float4 e4;
      e4.x = __expf(m4.x * ninv);
      e4.y = __expf(m4.y * ninv);
      e4.z = __expf(m4.z * ninv);
      e4.w = __expf(m4.w * ninv);
      const int col = (((row >> 2) ^ c4) << 2) | (row & 3);
      as[4 * c4 + 0][col] = e4.x;
      as[4 * c4 + 1][col] = e4.y;
      as[4 * c4 + 2][col] = e4.z;
      as[4 * c4 + 3][col] = e4.w;
    }
    __syncthreads();
    const int rg2 = rg >> 2;
#pragma unroll 2
    for (int kk = 0; kk < 64; kk += 4) {
      float4 b0 = *(float4*)&bs[(kk + 0) * NBB_ + c * 4];
      float4 b1 = *(float4*)&bs[(kk + 1) * NBB_ + c * 4];
      float4 b2 = *(float4*)&bs[(kk + 2) * NBB_ + c * 4];
      float4 b3 = *(float4*)&bs[(kk + 3) * NBB_ + c * 4];
#pragma unroll
      for (int i = 0; i < 4; ++i) {
        const int sw = (rg2 + 4 * i) << 2;          // (j>>2)<<2 for this row
        float4 a4 = *(float4*)&as[rg + 16 * i][kk ^ sw];
        acc[i][0] = fmaf(a4.x, b0.x, acc[i][0]);
        acc[i][1] = fmaf(a4.x, b0.y, acc[i][1]);
        acc[i][2] = fmaf(a4.x, b0.z, acc[i][2]);
        acc[i][3] = fmaf(a4.x, b0.w, acc[i][3]);
        acc[i][0] = fmaf(a4.y, b1.x, acc[i][0]);
        acc[i][1] = fmaf(a4.y, b1.y, acc[i][1]);
        acc[i][2] = fmaf(a4.y, b1.z, acc[i][2]);
        acc[i][3] = fmaf(a4.y, b1.w, acc[i][3]);
        acc[i][0] = fmaf(a4.z, b2.x, acc[i][0]);
        acc[i][1] = fmaf(a4.z, b2.y, acc[i][1]);
        acc[i][2] = fmaf(a4.z, b2.z, acc[i][2]);
        acc[i][3] = fmaf(a4.z, b2.w, acc[i][3]);
        acc[i][0] = fmaf(a4.w, b3.x, acc[i][0]);
        acc[i][1] = fmaf(a4.w, b3.y, acc[i][1]);
        acc[i][2] = fmaf(a4.w, b3.z, acc[i][2]);
        acc[i][3] = fmaf(a4.w, b3.w, acc[i][3]);
      }
    }
    __syncthreads();
  }
#pragma unroll
  for (int i = 0; i < 4; ++i) {
    const int row = r0 + rg + 16 * i;
    float4 o = make_float4(acc[i][0], acc[i][1], acc[i][2], acc[i][3]);
    *(float4*)&OutP[(size_t)ks * PART + row * NBB_ + c * 4] = o;
  }
}

// ---------------- r = b / sum_ks(CuP), flag any(Cu == 0) --------------------
__global__ void k_div_red(const float4* __restrict__ b4, const float* __restrict__ CuP,
                          float4* __restrict__ r4, int* __restrict__ badflag,
                          const int* __restrict__ act) {
  if (*act == 0) return;
  const int idx = blockIdx.x * blockDim.x + threadIdx.x;  // < 65536 (float4)
  float4 s = make_float4(0.f, 0.f, 0.f, 0.f);
#pragma unroll
  for (int k = 0; k < KSPLIT; ++k) {
    const float4 p = *(const float4*)&CuP[(size_t)k * PART + idx * 4];
    s.x += p.x; s.y += p.y; s.z += p.z; s.w += p.w;
  }
  const float4 bb = b4[idx];
  float4 rr;
  rr.x = bb.x / s.x;
  rr.y = bb.y / s.y;
  rr.z = bb.z / s.z;
  rr.w = bb.w / s.w;
  r4[idx] = rr;
  if (s.x == 0.0f || s.y == 0.0f || s.z == 0.0f || s.w == 0.0f)
    atomicOr(badflag, 1);
}

// ---------------- per-row: reduce VaP -> v_new; yhat, u_new, err sums -------
// one wave per row (64 lanes = 64 topics); u,v updated IN PLACE (safe: once
// an iteration is bad, all later iterations are inactive and u,v never feed
// the output -- only yhat does, and yhat commit stays conditional).
// Err sums: wave shfl-reduce -> LDS -> ONE 4-float partial per block, written
// non-atomically to Spart[block][4] (round-2 atomic storm: 213us -> gone).
__global__ void k_rowwise_red(const float* __restrict__ VaP, const float* __restrict__ lbd,
                              float* __restrict__ u, float* __restrict__ v,
                              float* __restrict__ yhnew, float* __restrict__ Spart,
                              int* __restrict__ nonfin, const int* __restrict__ act) {
  if (*act == 0) return;
  __shared__ float bred[4][4];
  const int lane = threadIdx.x & 63;
  const int wid  = threadIdx.x >> 6;
  const int row  = blockIdx.x * 4 + wid;
  const int idx  = row * NBB_ + lane;
  float vv = 0.0f;
#pragma unroll
  for (int k = 0; k < KSPLIT; ++k) vv += VaP[(size_t)k * PART + idx];
  float tsum = lbd[lane] * logf(vv);
#pragma unroll
  for (int o = 32; o > 0; o >>= 1) tsum += __shfl_xor(tsum, o);
  const float yhv = expf(tsum);          // prod_j v^lbd_j
  const float un  = yhv / vv;
  const float uo  = u[idx];
  const float vo  = v[idx];
  u[idx] = un;
  v[idx] = vv;
  if (lane == 0) yhnew[row] = yhv;
  if (!(finitef(un) && finitef(vv) && finitef(yhv))) atomicOr(nonfin, 1);
  const float du = un - uo;
  const float dv = vv - vo;
  float s0 = du * du, s1 = un * un, s2 = dv * dv, s3 = vv * vv;
#pragma unroll
  for (int o = 32; o > 0; o >>= 1) {
    s0 += __shfl_xor(s0, o);
    s1 += __shfl_xor(s1, o);
    s2 += __shfl_xor(s2, o);
    s3 += __shfl_xor(s3, o);
  }
  if (lane == 0) {
    bred[wid][0] = s0; bred[wid][1] = s1; bred[wid][2] = s2; bred[wid][3] = s3;
  }
  __syncthreads();
  if (threadIdx.x < 4)
    Spart[blockIdx.x * 4 + threadIdx.x] =
        bred[0][threadIdx.x] + bred[1][threadIdx.x] +
        bred[2][threadIdx.x] + bred[3][threadIdx.x];
}

// ---------------- commit: conditional yhat update + loop-control update -----
// Block 0 also reduces the 1024x4 err partials (deterministic, no atomics).
__global__ void k_commit(float* __restrict__ yhat, const float* __restrict__ yhnew,
                         const float* __restrict__ Spart, float* __restrict__ S,
                         int slot) {
  int* Si = (int*)S;
  const int active = Si[3 + slot];
  const int bad    = (Si[5 + slot] | Si[7 + slot]) != 0;
  const bool com   = (active != 0) && !bad;
  const int gid = blockIdx.x * blockDim.x + threadIdx.x;   // 4096 threads
  if (com && gid < NV) yhat[gid] = yhnew[gid];
  if (blockIdx.x == 0) {
    __shared__ float bred[4][4];
    const int t = threadIdx.x;
    const int c = t & 3;
    float s = 0.0f;
    for (int i = (t >> 2); i < 1024; i += 64) s += Spart[i * 4 + c];
#pragma unroll
    for (int o = 4; o < 64; o <<= 1) s += __shfl_xor(s, o);
    if ((t & 63) < 4) bred[t >> 6][t & 63] = s;   // lane c holds col-c sum
    __syncthreads();
    if (t == 0) {
      if (active) {
        if (!bad) {
          const int cpt = Si[1];
          if (cpt % 10 == 0) {
            const float t0 = bred[0][0] + bred[1][0] + bred[2][0] + bred[3][0];
            const float t1 = bred[0][1] + bred[1][1] + bred[2][1] + bred[3][1];
            const float t2 = bred[0][2] + bred[1][2] + bred[2][2] + bred[3][2];
            const float t3 = bred[0][3] + bred[1][3] + bred[2][3] + bred[3][3];
            S[0] = t0 / t1 + t2 / t3;    // err = lhs + rhs
          }
          Si[1] = cpt + 1;
        } else {
          Si[2] = 1;                     // broke
        }
      }
      const int ns = slot ^ 1;
      Si[3 + ns] = (S[0] > 1e-9f && Si[1] < ITERS && Si[2] == 0) ? 1 : 0;
      Si[5 + ns] = 0;
      Si[7 + ns] = 0;
    }
  }
}

// ---------------- out = sum((yhat - a)^2) -----------------------------------
__global__ void k_final(const float* __restrict__ yhat, const float* __restrict__ a,
                        float* __restrict__ out) {
  __shared__ float red[4];
  const int t = threadIdx.x;
  float s = 0.0f;
  for (int i = t; i < NV; i += 256) {
    const float d = yhat[i] - a[i];
    s = fmaf(d, d, s);
  }
#pragma unroll
  for (int o = 32; o > 0; o >>= 1) s += __shfl_xor(s, o);
  if ((t & 63) == 0) red[t >> 6] = s;
  __syncthreads();
  if (t == 0) out[0] = red[0] + red[1] + red[2] + red[3];
}

extern "C" void kernel_launch(void* const* d_in, const int* in_sizes, int n_in,
                              void* d_out, int out_size, void* d_ws, size_t ws_size,
                              hipStream_t stream) {
  const float* a   = (const float*)d_in[0];
  const float* M   = (const float*)d_in[1];
  const float* b   = (const float*)d_in[2];
  const float* lbd = (const float*)d_in[3];
  const float* reg = (const float*)d_in[4];
  float* out = (float*)d_out;

  float* ws = (float*)d_ws;
  size_t o = 0;
  float* part  = ws + o; o += (size_t)KSPLIT * PART;  // 16 MB, reused by both GEMMs
  float* r     = ws + o; o += PART;
  float* u     = ws + o; o += PART;
  float* v     = ws + o; o += PART;
  float* yh    = ws + o; o += NV;
  float* yhn   = ws + o; o += NV;
  float* S     = ws + o; o += 64;
  float* Spart = ws + o; o += 1024 * 4;
  int* Si = (int*)S;

  k_init<<<dim3(1024), dim3(256), 0, stream>>>(u, v, yh, S);

  for (int it = 0; it < ITERS; ++it) {
    const int slot = it & 1;
    const int* act = (const int*)(Si + 3 + slot);
    k_gemm_e<<<dim3(1024), dim3(256), 0, stream>>>(M, reg, u, part, act);
    k_div_red<<<dim3(256), dim3(256), 0, stream>>>((const float4*)b, part,
                                                   (float4*)r, Si + 5 + slot, act);
    k_gemm_te<<<dim3(1024), dim3(256), 0, stream>>>(M, reg, r, part, act);
    k_rowwise_red<<<dim3(1024), dim3(256), 0, stream>>>(part, lbd, u, v, yhn,
                                                        Spart, Si + 7 + slot, act);
    k_commit<<<dim3(16), dim3(256), 0, stream>>>(yh, yhn, Spart, S, slot);
  }

  k_final<<<dim3(1), dim3(256), 0, stream>>>(yh, a, out);
}

// Round 4
// 1155.069 us; speedup vs baseline: 2.7488x; 1.0391x over previous
//
#include <hip/hip_runtime.h>

// WasserIndexGen: Wasserstein barycenter Sinkhorn (N=4096, NBB=64, <=30 iters).
// Round-4: bf16 MFMA GEMMs. C = bf16(exp(-M/reg)) materialized ONCE (32 MB,
// L3-resident). GEMM2 (C^T @ r) reads the same Cbf with transpose-staging into
// an XOR-swizzled LDS tile. Split-K (16) writes deterministic TRANSPOSED
// partials [ks][col][row] (native MFMA D-layout, float4 stores). Producers
// write B-operands as bf16 col-major (uT, rT) so GEMM B-staging is a plain
// copy. Loop control device-side (flags in S), commit fused into rowwise via
// device-scope ticket; inactive iterations propagate the inactive flag.
//
// ws (~55 MB): part f32[16][64][4096], Cbf bf16[4096][4096], bT f32[64][4096],
// uT/rT bf16[64][4096], u/v f32[4096][64], yh/yhn[4096], S[64], Spart[64*4].

typedef __attribute__((ext_vector_type(8))) short bf16x8;
typedef __attribute__((ext_vector_type(8))) unsigned short u16x8;
typedef __attribute__((ext_vector_type(4))) float f32x4;

constexpr int NV     = 4096;
constexpr int NBB_   = 64;
constexpr int ITERS  = 30;
constexpr int KSPLIT = 16;              // k-slices of 256
constexpr int PART   = NV * NBB_;       // floats per partial slice [64][4096]

__device__ __forceinline__ bool finitef(float x) {
  return __builtin_fabsf(x) <= 3.402823466e38f;  // false for NaN/inf
}

__device__ __forceinline__ unsigned short f2bf(float x) {  // RNE f32->bf16
  unsigned int u = __builtin_bit_cast(unsigned int, x);
  return (unsigned short)((u + 0x7fffu + ((u >> 16) & 1u)) >> 16);
}

// LDS A-tile swizzle: 16B-block index XORed with row bits -> bank-even b128
// reads AND bank-even column writes (transpose staging). Returns ushort index.
__device__ __forceinline__ int aswz(int row, int colblk) {
  return row * 64 + (((colblk) ^ (row & 7) ^ (row >> 3)) << 3);
}

// ---------------- setup: iterates, bT transpose, control ---------------------
__global__ void k_setup(const float* __restrict__ b, float* __restrict__ u,
                        float* __restrict__ v, unsigned short* __restrict__ uT,
                        float* __restrict__ bT, float* __restrict__ yh,
                        float* __restrict__ S) {
  const int gid = blockIdx.x * blockDim.x + threadIdx.x;  // 16384 threads
  for (int i = gid; i < NV * NBB_; i += 16384) {
    u[i] = 1.0f; v[i] = 1.0f; uT[i] = 0x3F80;  // bf16(1.0)
  }
  for (int i = gid; i < NV * NBB_ / 4; i += 16384) {
    const int col = i >> 10;
    const int r4  = (i & 1023) * 4;
#pragma unroll
    for (int q = 0; q < 4; ++q) bT[col * NV + r4 + q] = b[(r4 + q) * NBB_ + col];
  }
  for (int i = gid; i < NV; i += 16384) yh[i] = 0.0f;
  if (gid == 0) {
    int* Si = (int*)S;
    S[0]  = 1.0f;          // err
    Si[1] = 0;             // cpt
    Si[2] = 0;             // broke
    Si[3] = 1; Si[4] = 0;  // active[slot]
    Si[5] = 0; Si[6] = 0;  // badCu[slot]
    Si[7] = 0; Si[8] = 0;  // nonfin[slot]
#pragma unroll
    for (int q = 16; q < 48; ++q) Si[q] = 0;  // tickets[it]
  }
}

// ---------------- Cbf = bf16(exp(-M/reg)) -----------------------------------
__global__ void k_cgen(const float* __restrict__ M, const float* __restrict__ regp,
                       unsigned short* __restrict__ Cb) {
  const float ninv = -1.0f / regp[0];
  const size_t i0 = ((size_t)blockIdx.x * 256 + threadIdx.x) * 16;
#pragma unroll
  for (int q = 0; q < 2; ++q) {
    const float4 m0 = *(const float4*)&M[i0 + q * 8];
    const float4 m1 = *(const float4*)&M[i0 + q * 8 + 4];
    u16x8 o;
    o[0] = f2bf(__expf(m0.x * ninv));
    o[1] = f2bf(__expf(m0.y * ninv));
    o[2] = f2bf(__expf(m0.z * ninv));
    o[3] = f2bf(__expf(m0.w * ninv));
    o[4] = f2bf(__expf(m1.x * ninv));
    o[5] = f2bf(__expf(m1.y * ninv));
    o[6] = f2bf(__expf(m1.z * ninv));
    o[7] = f2bf(__expf(m1.w * ninv));
    *(u16x8*)&Cb[i0 + q * 8] = o;
  }
}

// ---------------- MFMA GEMM: OutP[ks] = (A or A^T) @ B ----------------------
// A bf16 row-major [4096][4096]; B given as BT bf16 [64][4096] (B[k][j]=BT[j][k]).
// grid = 64 rowtiles x 16 ksplits = 1024 blocks, 256 thr (4 waves).
// Block: 64 rows x 64 cols, K-slice 256 in 4 chunks of 64.
// Wave w: rows [16w,16w+16), 4 col-tiles. Output TRANSPOSED [ks][col][row].
template <bool TRANSA>
__global__ __launch_bounds__(256, 4) void k_gemm_mf(
    const unsigned short* __restrict__ A, const unsigned short* __restrict__ BT,
    float* __restrict__ OutP, const int* __restrict__ act) {
  if (*act == 0) return;
  __shared__ unsigned short as_[64 * 64];  // swizzled (aswz)
  __shared__ unsigned short bsT[64 * 72];  // [col][k] padded
  const int rt = blockIdx.x >> 4;
  const int ks = blockIdx.x & 15;
  const int r0 = rt * 64;
  const int k0 = ks * 256;
  const int t  = threadIdx.x;
  const int w    = t >> 6;
  const int lane = t & 63;
  const int lr   = lane & 15;
  const int lg   = lane >> 4;
  f32x4 acc[4] = {};
  for (int ck = 0; ck < 4; ++ck) {
    const int kb = k0 + ck * 64;
    // stage B: 64 cols x 64 k (plain bf16 copy, [col][k])
#pragma unroll
    for (int s = 0; s < 2; ++s) {
      const int l = s * 256 + t;
      const int col = l >> 3, k8 = l & 7;
      *(u16x8*)&bsT[col * 72 + k8 * 8] =
          *(const u16x8*)&BT[(size_t)col * NV + kb + k8 * 8];
    }
    // stage A: 64 rows x 64 k into swizzled tile
    if (!TRANSA) {
#pragma unroll
      for (int s = 0; s < 2; ++s) {
        const int l = s * 256 + t;
        const int row = l >> 3, cb = l & 7;
        *(u16x8*)&as_[aswz(row, cb)] =
            *(const u16x8*)&A[(size_t)(r0 + row) * NV + kb + cb * 8];
      }
    } else {
      // A^T tile: read C rows (k), scatter columns into swizzled LDS
#pragma unroll
      for (int s = 0; s < 2; ++s) {
        const int l = s * 256 + t;
        const int krow = l >> 3, i8 = l & 7;
        const u16x8 m = *(const u16x8*)&A[(size_t)(kb + krow) * NV + r0 + i8 * 8];
#pragma unroll
        for (int e = 0; e < 8; ++e)
          as_[aswz(i8 * 8 + e, krow >> 3) + (krow & 7)] = m[e];
      }
    }
    __syncthreads();
#pragma unroll
    for (int kk = 0; kk < 64; kk += 32) {
      const bf16x8 af = *(const bf16x8*)&as_[aswz(w * 16 + lr, (kk >> 3) + lg)];
#pragma unroll
      for (int ct = 0; ct < 4; ++ct) {
        const bf16x8 bf = *(const bf16x8*)&bsT[(ct * 16 + lr) * 72 + kk + lg * 8];
        acc[ct] = __builtin_amdgcn_mfma_f32_16x16x32_bf16(af, bf, acc[ct], 0, 0, 0);
      }
    }
    __syncthreads();
  }
#pragma unroll
  for (int ct = 0; ct < 4; ++ct) {
    const int col = ct * 16 + lr;
    *(f32x4*)&OutP[(size_t)ks * PART + (size_t)col * NV + r0 + w * 16 + lg * 4] =
        acc[ct];
  }
}

// ---------------- r^T = bT / reduce(CuP), bf16; flag any(Cu==0) -------------
__global__ void k_div_red(const float* __restrict__ bT, const float* __restrict__ CuP,
                          unsigned short* __restrict__ rT, int* __restrict__ badflag,
                          const int* __restrict__ act) {
  if (*act == 0) return;
  const int idx = blockIdx.x * blockDim.x + threadIdx.x;  // 65536
  const int col = idx >> 10;
  const int r4  = (idx & 1023) * 4;
  const size_t off = (size_t)col * NV + r4;
  float4 s = make_float4(0.f, 0.f, 0.f, 0.f);
#pragma unroll
  for (int k = 0; k < KSPLIT; ++k) {
    const float4 p = *(const float4*)&CuP[(size_t)k * PART + off];
    s.x += p.x; s.y += p.y; s.z += p.z; s.w += p.w;
  }
  const float4 bb = *(const float4*)&bT[off];
  if (s.x == 0.f || s.y == 0.f || s.z == 0.f || s.w == 0.f) atomicOr(badflag, 1);
  ushort4 rr;
  rr.x = f2bf(bb.x / s.x);
  rr.y = f2bf(bb.y / s.y);
  rr.z = f2bf(bb.z / s.z);
  rr.w = f2bf(bb.w / s.w);
  *(ushort4*)&rT[off] = rr;
}

// ---------------- rowwise (v,yhat,u,err) + fused commit (ticket) ------------
// grid 64 x 256; 4 threads per row, 16 cols each.
__global__ __launch_bounds__(256, 4) void k_rowwise_commit(
    const float* __restrict__ VaP, const float* __restrict__ lbd,
    float* __restrict__ u, float* __restrict__ v,
    unsigned short* __restrict__ uT, float* __restrict__ yhat,
    float* __restrict__ yhnew, float* __restrict__ Spart,
    float* __restrict__ S, int it) {
  int* Si = (int*)S;
  const int slot = it & 1;
  if (Si[3 + slot] == 0) {
    if (blockIdx.x == 0 && threadIdx.x == 0) Si[3 + (slot ^ 1)] = 0;
    return;
  }
  const int t   = threadIdx.x;
  const int row = blockIdx.x * 64 + (t >> 2);
  const int sub = t & 3;
  const int cb  = sub * 16;
  float vv[16];
#pragma unroll
  for (int c = 0; c < 16; ++c) {
    float s = 0.f;
#pragma unroll
    for (int k = 0; k < KSPLIT; ++k)
      s += VaP[(size_t)k * PART + (size_t)(cb + c) * NV + row];
    vv[c] = s;
  }
  float tq = 0.f;
#pragma unroll
  for (int c = 0; c < 16; ++c) tq += lbd[cb + c] * __logf(vv[c]);
  tq += __shfl_xor(tq, 1);
  tq += __shfl_xor(tq, 2);
  const float yhv = __expf(tq);  // prod_j v^lbd_j
  if (sub == 0) yhnew[row] = yhv;
  float s0 = 0.f, s1 = 0.f, s2 = 0.f, s3 = 0.f;
  bool bad = !finitef(yhv);
#pragma unroll
  for (int c = 0; c < 16; ++c) {
    const int idx = row * NBB_ + cb + c;
    const float un = yhv / vv[c];
    const float uo = u[idx];
    const float vo = v[idx];
    u[idx] = un;
    v[idx] = vv[c];
    uT[(size_t)(cb + c) * NV + row] = f2bf(un);
    const float du = un - uo, dv = vv[c] - vo;
    s0 += du * du; s1 += un * un; s2 += dv * dv; s3 += vv[c] * vv[c];
    bad |= !(finitef(un) && finitef(vv[c]));
  }
  if (bad) atomicOr(&Si[7 + slot], 1);
#pragma unroll
  for (int o = 1; o < 64; o <<= 1) {
    s0 += __shfl_xor(s0, o); s1 += __shfl_xor(s1, o);
    s2 += __shfl_xor(s2, o); s3 += __shfl_xor(s3, o);
  }
  __shared__ float wred[4][4];
  __shared__ int lastflag;
  if ((t & 63) == 0) {
    wred[t >> 6][0] = s0; wred[t >> 6][1] = s1;
    wred[t >> 6][2] = s2; wred[t >> 6][3] = s3;
  }
  __syncthreads();
  if (t < 4)
    Spart[blockIdx.x * 4 + t] =
        wred[0][t] + wred[1][t] + wred[2][t] + wred[3][t];
  if (t == 0) {
    __threadfence();
    lastflag = (atomicAdd(&Si[16 + it], 1) == (int)gridDim.x - 1);
  }
  __syncthreads();
  if (!lastflag) return;
  __threadfence();
  // ---- commit (last block) ----
  const bool com = ((Si[5 + slot] | Si[7 + slot]) == 0);
  __shared__ float cred[4][4];
  {
    float s = Spart[(t >> 2) * 4 + (t & 3)];  // t>>2 in [0,64) == grid size
#pragma unroll
    for (int o = 4; o < 64; o <<= 1) s += __shfl_xor(s, o);
    if ((t & 63) < 4) cred[t >> 6][t & 3] = s;
  }
  __syncthreads();
  if (t == 0) {
    if (com) {
      const int cpt = Si[1];
      if (cpt % 10 == 0) {
        const float q0 = cred[0][0] + cred[1][0] + cred[2][0] + cred[3][0];
        const float q1 = cred[0][1] + cred[1][1] + cred[2][1] + cred[3][1];
        const float q2 = cred[0][2] + cred[1][2] + cred[2][2] + cred[3][2];
        const float q3 = cred[0][3] + cred[1][3] + cred[2][3] + cred[3][3];
        S[0] = q0 / q1 + q2 / q3;  // err = lhs + rhs
      }
      Si[1] = cpt + 1;
    } else {
      Si[2] = 1;  // broke
    }
    const int ns = slot ^ 1;
    Si[3 + ns] = (S[0] > 1e-9f && Si[1] < ITERS && Si[2] == 0) ? 1 : 0;
    Si[5 + ns] = 0;
    Si[7 + ns] = 0;
  }
  if (com)
    for (int i = t; i < NV; i += 256) yhat[i] = yhnew[i];
}

// ---------------- out = sum((yhat - a)^2) -----------------------------------
__global__ void k_final(const float* __restrict__ yhat, const float* __restrict__ a,
                        float* __restrict__ out) {
  __shared__ float red[4];
  const int t = threadIdx.x;
  float s = 0.0f;
  for (int i = t; i < NV; i += 256) {
    const float d = yhat[i] - a[i];
    s = fmaf(d, d, s);
  }
#pragma unroll
  for (int o = 32; o > 0; o >>= 1) s += __shfl_xor(s, o);
  if ((t & 63) == 0) red[t >> 6] = s;
  __syncthreads();
  if (t == 0) out[0] = red[0] + red[1] + red[2] + red[3];
}

extern "C" void kernel_launch(void* const* d_in, const int* in_sizes, int n_in,
                              void* d_out, int out_size, void* d_ws, size_t ws_size,
                              hipStream_t stream) {
  const float* a   = (const float*)d_in[0];
  const float* M   = (const float*)d_in[1];
  const float* b   = (const float*)d_in[2];
  const float* lbd = (const float*)d_in[3];
  const float* reg = (const float*)d_in[4];
  float* out = (float*)d_out;

  char* wsb = (char*)d_ws;
  size_t off = 0;
  auto alloc = [&](size_t bytes) -> void* {
    void* p = wsb + off;
    off += (bytes + 255) & ~(size_t)255;
    return p;
  };
  float*          part  = (float*)alloc(sizeof(float) * (size_t)KSPLIT * PART);
  unsigned short* Cbf   = (unsigned short*)alloc(2 * (size_t)NV * NV);
  float*          bT    = (float*)alloc(sizeof(float) * (size_t)PART);
  unsigned short* uT    = (unsigned short*)alloc(2 * (size_t)PART);
  unsigned short* rT    = (unsigned short*)alloc(2 * (size_t)PART);
  float*          u     = (float*)alloc(sizeof(float) * (size_t)PART);
  float*          v     = (float*)alloc(sizeof(float) * (size_t)PART);
  float*          yh    = (float*)alloc(sizeof(float) * NV);
  float*          yhn   = (float*)alloc(sizeof(float) * NV);
  float*          S     = (float*)alloc(sizeof(float) * 64);
  float*          Spart = (float*)alloc(sizeof(float) * 64 * 4);
  int* Si = (int*)S;

  k_setup<<<dim3(64), dim3(256), 0, stream>>>(b, u, v, uT, bT, yh, S);
  k_cgen<<<dim3(4096), dim3(256), 0, stream>>>(M, reg, Cbf);

  for (int it = 0; it < ITERS; ++it) {
    const int slot = it & 1;
    const int* act = (const int*)(Si + 3 + slot);
    k_gemm_mf<false><<<dim3(1024), dim3(256), 0, stream>>>(Cbf, uT, part, act);
    k_div_red<<<dim3(256), dim3(256), 0, stream>>>(bT, part, rT, Si + 5 + slot, act);
    k_gemm_mf<true><<<dim3(1024), dim3(256), 0, stream>>>(Cbf, rT, part, act);
    k_rowwise_commit<<<dim3(64), dim3(256), 0, stream>>>(part, lbd, u, v, uT, yh,
                                                         yhn, Spart, S, it);
  }

  k_final<<<dim3(1), dim3(256), 0, stream>>>(yh, a, out);
}